// Round 6
// baseline (561.339 us; speedup 1.0000x reference)
//
#include <hip/hip_runtime.h>

#define N_NODES 100000
#define N_EDGES 1600000
#define FEATS 48
#define BSH 6                       /* 64-node buckets */
#define BUCK 64
#define NB ((N_NODES + BUCK - 1) / BUCK)   /* 1563 */
#define EPB 8192                    /* edges per partition block */
#define PBLK ((N_EDGES + EPB - 1) / EPB)   /* 196 */
#define EBATCH 1024                 /* edges staged in LDS per batch */

// ---- pass 1: per-bucket edge counts (LDS hist -> global atomics) ----
__global__ __launch_bounds__(256) void bucket_count(const int* __restrict__ dst,
                                                    int* __restrict__ cnt) {
    __shared__ int hist[NB];
    int tid = threadIdx.x;
    for (int i = tid; i < NB; i += 256) hist[i] = 0;
    __syncthreads();
    int e0 = blockIdx.x * EPB;
#pragma unroll
    for (int i = 0; i < EPB / 256; ++i) {
        int e = e0 + i * 256 + tid;
        if (e < N_EDGES) atomicAdd(&hist[dst[e] >> BSH], 1);
    }
    __syncthreads();
    for (int i = tid; i < NB; i += 256)
        if (hist[i]) atomicAdd(&cnt[i], hist[i]);
}

// ---- pass 2: exclusive scan of cnt[NB] (single block) ----
__global__ __launch_bounds__(256) void bucket_scan(const int* __restrict__ cnt,
                                                   int* __restrict__ base,
                                                   int* __restrict__ cur) {
    __shared__ int warr[256];
    const int PER = (NB + 255) / 256;  // 7
    int t = threadIdx.x;
    int v[7], s = 0;
#pragma unroll
    for (int j = 0; j < PER; ++j) {
        int i = t * PER + j;
        v[j] = (i < NB) ? cnt[i] : 0;
        s += v[j];
    }
    warr[t] = s;
    __syncthreads();
    for (int d = 1; d < 256; d <<= 1) {
        int x = (t >= d) ? warr[t - d] : 0;
        __syncthreads();
        warr[t] += x;
        __syncthreads();
    }
    int excl = warr[t] - s;
#pragma unroll
    for (int j = 0; j < PER; ++j) {
        int i = t * PER + j;
        if (i < NB) { base[i] = excl; cur[i] = excl; }
        excl += v[j];
    }
}

// ---- pass 3: scatter packed (src<<6 | dst&63) into exact bucket segments ----
__global__ __launch_bounds__(256) void bucket_scatter(const int* __restrict__ src,
                                                      const int* __restrict__ dst,
                                                      int* __restrict__ cur,
                                                      int* __restrict__ packed) {
    __shared__ int hist[NB];
    __shared__ int lbase[NB];
    int tid = threadIdx.x;
    for (int i = tid; i < NB; i += 256) hist[i] = 0;
    __syncthreads();
    int e0 = blockIdx.x * EPB;
#pragma unroll
    for (int i = 0; i < EPB / 256; ++i) {
        int e = e0 + i * 256 + tid;
        if (e < N_EDGES) atomicAdd(&hist[dst[e] >> BSH], 1);
    }
    __syncthreads();
    for (int i = tid; i < NB; i += 256) {
        int h = hist[i];
        lbase[i] = h ? atomicAdd(&cur[i], h) : 0;
        hist[i] = 0;   // reuse as local cursor
    }
    __syncthreads();
#pragma unroll
    for (int i = 0; i < EPB / 256; ++i) {
        int e = e0 + i * 256 + tid;
        if (e < N_EDGES) {
            int d = dst[e], s = src[e];
            int k = d >> BSH;
            int pos = lbase[k] + atomicAdd(&hist[k], 1);
            packed[pos] = (s << BSH) | (d & (BUCK - 1));
        }
    }
}

// ---- pass 4: one block per 64-node bucket ----
// R6 rewrite: lane = feature column (R2's proven pattern). Edge words staged
// in LDS; 8 independent scalar feature loads in flight per wave (named regs,
// addresses from LDS -> no shuffle in the dependence chain); one ds_add_f32
// per edge per lane (<=2-way bank alias = free).
__global__ __launch_bounds__(256) void aggregate_kernel(
    const float* __restrict__ feature, const int* __restrict__ packed,
    const int* __restrict__ base, const int* __restrict__ cnt,
    const float* __restrict__ W, const float* __restrict__ bias,
    float* __restrict__ out) {
    __shared__ float accS[BUCK][FEATS];   // 12.3 KB
    __shared__ float degS[BUCK];
    __shared__ float Wt[FEATS * FEATS];   // 9.2 KB, Wt[f*48+o] = W[o*48+f]
    __shared__ int eidL[EBATCH];          // 4 KB
    int tid = threadIdx.x;
    float* af = &accS[0][0];
    for (int i = tid; i < BUCK * FEATS; i += 256) af[i] = 0.f;
    if (tid < BUCK) degS[tid] = 0.f;
    for (int i = tid; i < FEATS * FEATS; i += 256) {
        int o = i / FEATS, f = i - o * FEATS;
        Wt[f * FEATS + o] = W[i];
    }
    __syncthreads();

    int k = blockIdx.x;
    int c = cnt[k];
    const int* __restrict__ ep = packed + base[k];
    int wave = tid >> 6, lane = tid & 63;
    int lc = (lane < FEATS) ? lane : (FEATS - 1);  // clamped col (lanes 48-63 redundant)

    for (int b0 = 0; b0 < c; b0 += EBATCH) {
        int bn = c - b0; if (bn > EBATCH) bn = EBATCH;
        for (int i = tid; i < bn; i += 256) eidL[i] = ep[b0 + i];
        __syncthreads();

        int per = (bn + 3) >> 2;
        int lo = wave * per;
        int hi = lo + per; if (hi > bn) hi = bn;

        int i = lo;
        for (; i + 8 <= hi; i += 8) {
            int pe0 = eidL[i+0], pe1 = eidL[i+1], pe2 = eidL[i+2], pe3 = eidL[i+3];
            int pe4 = eidL[i+4], pe5 = eidL[i+5], pe6 = eidL[i+6], pe7 = eidL[i+7];
            float v0 = feature[(size_t)(pe0 >> BSH) * FEATS + lc];
            float v1 = feature[(size_t)(pe1 >> BSH) * FEATS + lc];
            float v2 = feature[(size_t)(pe2 >> BSH) * FEATS + lc];
            float v3 = feature[(size_t)(pe3 >> BSH) * FEATS + lc];
            float v4 = feature[(size_t)(pe4 >> BSH) * FEATS + lc];
            float v5 = feature[(size_t)(pe5 >> BSH) * FEATS + lc];
            float v6 = feature[(size_t)(pe6 >> BSH) * FEATS + lc];
            float v7 = feature[(size_t)(pe7 >> BSH) * FEATS + lc];
            if (lane < FEATS) {
                atomicAdd(&accS[pe0 & (BUCK-1)][lane], v0);
                atomicAdd(&accS[pe1 & (BUCK-1)][lane], v1);
                atomicAdd(&accS[pe2 & (BUCK-1)][lane], v2);
                atomicAdd(&accS[pe3 & (BUCK-1)][lane], v3);
                atomicAdd(&accS[pe4 & (BUCK-1)][lane], v4);
                atomicAdd(&accS[pe5 & (BUCK-1)][lane], v5);
                atomicAdd(&accS[pe6 & (BUCK-1)][lane], v6);
                atomicAdd(&accS[pe7 & (BUCK-1)][lane], v7);
            } else if (lane == FEATS) {
                atomicAdd(&degS[pe0 & (BUCK-1)], 1.0f);
                atomicAdd(&degS[pe1 & (BUCK-1)], 1.0f);
                atomicAdd(&degS[pe2 & (BUCK-1)], 1.0f);
                atomicAdd(&degS[pe3 & (BUCK-1)], 1.0f);
                atomicAdd(&degS[pe4 & (BUCK-1)], 1.0f);
                atomicAdd(&degS[pe5 & (BUCK-1)], 1.0f);
                atomicAdd(&degS[pe6 & (BUCK-1)], 1.0f);
                atomicAdd(&degS[pe7 & (BUCK-1)], 1.0f);
            }
        }
        for (; i < hi; ++i) {
            int pe = eidL[i];
            float v = feature[(size_t)(pe >> BSH) * FEATS + lc];
            if (lane < FEATS)        atomicAdd(&accS[pe & (BUCK-1)][lane], v);
            else if (lane == FEATS)  atomicAdd(&degS[pe & (BUCK-1)], 1.0f);
        }
        __syncthreads();
    }

    int nbase = k * BUCK;
    float bv = (lane < FEATS) ? bias[lane] : 0.f;
    for (int nd = wave; nd < BUCK; nd += 4) {
        int gn = nbase + nd;
        if (gn >= N_NODES) break;
        if (lane < FEATS) {
            float inv = 1.0f / fmaxf(degS[nd], 1.0f);
            float r = 0.f;
#pragma unroll
            for (int f = 0; f < FEATS; ++f)
                r += accS[nd][f] * Wt[f * FEATS + lane];  // accS broadcast, Wt 2-way max
            out[(size_t)gn * FEATS + lane] = bv + inv * r;
        }
    }
}

// ---------------- CSR fallback (R2, known-good 322us) ----------------

__global__ void count_kernel(const int* __restrict__ dst, int* __restrict__ cnt) {
    int e = blockIdx.x * blockDim.x + threadIdx.x;
    if (e < N_EDGES) atomicAdd(&cnt[dst[e]], 1);
}

__global__ void offsets_kernel(const int* __restrict__ cnt, int* __restrict__ gcounter,
                               int* __restrict__ off, int* __restrict__ cur) {
    int n = blockIdx.x * blockDim.x + threadIdx.x;
    int lane = threadIdx.x & 63;
    int c = (n < N_NODES) ? cnt[n] : 0;
    int incl = c;
#pragma unroll
    for (int d = 1; d < 64; d <<= 1) {
        int v = __shfl_up(incl, d);
        if (lane >= d) incl += v;
    }
    int wtot = __shfl(incl, 63);
    int b0 = 0;
    if (lane == 63) b0 = atomicAdd(gcounter, wtot);
    b0 = __shfl(b0, 63);
    int o = b0 + incl - c;
    if (n < N_NODES) { off[n] = o; cur[n] = o; }
}

__global__ void scatter_kernel(const int* __restrict__ src, const int* __restrict__ dst,
                               int* __restrict__ cur, int* __restrict__ eid) {
    int e = blockIdx.x * blockDim.x + threadIdx.x;
    if (e < N_EDGES) {
        int p = atomicAdd(&cur[dst[e]], 1);
        eid[p] = src[e];
    }
}

__global__ __launch_bounds__(256) void gather_kernel(
    const float* __restrict__ feature,
    const int* __restrict__ cnt, const int* __restrict__ off,
    const int* __restrict__ eid,
    const float* __restrict__ W, const float* __restrict__ b,
    float* __restrict__ out) {
    __shared__ float Wt[FEATS * FEATS];
    __shared__ float meanS[4][FEATS];
    int tid = threadIdx.x;
    for (int i = tid; i < FEATS * FEATS; i += 256) {
        int o = i / FEATS, f = i - o * FEATS;
        Wt[f * FEATS + o] = W[i];
    }
    __syncthreads();
    int wave = tid >> 6, lane = tid & 63;
    int n = blockIdx.x * 4 + wave;
    if (n >= N_NODES) return;
    int c = cnt[n];
    int o = off[n];
    if (lane < FEATS) {
        float acc = 0.f;
        int t = lane, i = 0;
        for (; i + 4 <= c; i += 4) {
            int s0 = eid[o + i], s1 = eid[o + i + 1], s2 = eid[o + i + 2], s3 = eid[o + i + 3];
            acc += feature[s0 * FEATS + t];
            acc += feature[s1 * FEATS + t];
            acc += feature[s2 * FEATS + t];
            acc += feature[s3 * FEATS + t];
        }
        for (; i < c; ++i) acc += feature[eid[o + i] * FEATS + t];
        meanS[wave][t] = acc / fmaxf((float)c, 1.0f);
        float r = b[t];
#pragma unroll
        for (int f = 0; f < FEATS; ++f) r += meanS[wave][f] * Wt[f * FEATS + t];
        out[n * FEATS + t] = r;
    }
}

extern "C" void kernel_launch(void* const* d_in, const int* in_sizes, int n_in,
                              void* d_out, int out_size, void* d_ws, size_t ws_size,
                              hipStream_t stream) {
    const float* feature = (const float*)d_in[0];
    const float* W       = (const float*)d_in[1];
    const float* b       = (const float*)d_in[2];
    const int*   src     = (const int*)d_in[3];
    const int*   dst     = (const int*)d_in[4];
    float* out = (float*)d_out;

    // radix path ws: cnt[NB] | base[NB] | cur[NB] | packed[N_EDGES]
    const size_t need_radix = ((size_t)3 * NB + N_EDGES) * sizeof(int);
    if (ws_size >= need_radix) {
        int* I = (int*)d_ws;
        int* cnt    = I;
        int* base   = I + NB;
        int* cur    = I + 2 * NB;
        int* packed = I + 3 * NB;
        hipMemsetAsync(cnt, 0, NB * sizeof(int), stream);
        bucket_count  <<<PBLK, 256, 0, stream>>>(dst, cnt);
        bucket_scan   <<<1, 256, 0, stream>>>(cnt, base, cur);
        bucket_scatter<<<PBLK, 256, 0, stream>>>(src, dst, cur, packed);
        aggregate_kernel<<<NB, 256, 0, stream>>>(feature, packed,
                                                 base, cnt, W, b, out);
        return;
    }

    // CSR fallback
    const size_t need_csr = ((size_t)3 * N_NODES + 1 + N_EDGES) * sizeof(int);
    if (ws_size >= need_csr) {
        int* I = (int*)d_ws;
        int* cnt = I;
        int* gcounter = I + N_NODES;
        int* off = I + N_NODES + 1;
        int* cur = off + N_NODES;
        int* eid = cur + N_NODES;
        hipMemsetAsync(cnt, 0, (size_t)(N_NODES + 1) * sizeof(int), stream);
        int eb = (N_EDGES + 255) / 256;
        count_kernel<<<eb, 256, 0, stream>>>(dst, cnt);
        int nb = (N_NODES + 255) / 256;
        offsets_kernel<<<nb, 256, 0, stream>>>(cnt, gcounter, off, cur);
        scatter_kernel<<<eb, 256, 0, stream>>>(src, dst, cur, eid);
        gather_kernel<<<(N_NODES + 3) / 4, 256, 0, stream>>>(feature, cnt, off, eid, W, b, out);
    }
}

// Round 7
// 170.407 us; speedup vs baseline: 3.2941x; 3.2941x over previous
//
#include <hip/hip_runtime.h>

#define N_NODES 100000
#define N_EDGES 1600000
#define FEATS 48
#define BSH 6                       /* 64-node buckets */
#define BUCK 64
#define NB ((N_NODES + BUCK - 1) / BUCK)   /* 1563 */
#define EPB 8192                    /* edges per partition block */
#define PBLK ((N_EDGES + EPB - 1) / EPB)   /* 196 */

// ---- pass 1: per-bucket edge counts (LDS hist -> global atomics) ----
__global__ __launch_bounds__(256) void bucket_count(const int* __restrict__ dst,
                                                    int* __restrict__ cnt) {
    __shared__ int hist[NB];
    int tid = threadIdx.x;
    for (int i = tid; i < NB; i += 256) hist[i] = 0;
    __syncthreads();
    int e0 = blockIdx.x * EPB;
#pragma unroll
    for (int i = 0; i < EPB / 256; ++i) {
        int e = e0 + i * 256 + tid;
        if (e < N_EDGES) atomicAdd(&hist[dst[e] >> BSH], 1);
    }
    __syncthreads();
    for (int i = tid; i < NB; i += 256)
        if (hist[i]) atomicAdd(&cnt[i], hist[i]);
}

// ---- pass 2: exclusive scan of cnt[NB] (single block) ----
__global__ __launch_bounds__(256) void bucket_scan(const int* __restrict__ cnt,
                                                   int* __restrict__ base,
                                                   int* __restrict__ cur) {
    __shared__ int warr[256];
    const int PER = (NB + 255) / 256;  // 7
    int t = threadIdx.x;
    int v[7], s = 0;
#pragma unroll
    for (int j = 0; j < PER; ++j) {
        int i = t * PER + j;
        v[j] = (i < NB) ? cnt[i] : 0;
        s += v[j];
    }
    warr[t] = s;
    __syncthreads();
    for (int d = 1; d < 256; d <<= 1) {
        int x = (t >= d) ? warr[t - d] : 0;
        __syncthreads();
        warr[t] += x;
        __syncthreads();
    }
    int excl = warr[t] - s;
#pragma unroll
    for (int j = 0; j < PER; ++j) {
        int i = t * PER + j;
        if (i < NB) { base[i] = excl; cur[i] = excl; }
        excl += v[j];
    }
}

// ---- pass 3: scatter packed (src<<6 | dst&63) into bucket segments ----
__global__ __launch_bounds__(256) void bucket_scatter(const int* __restrict__ src,
                                                      const int* __restrict__ dst,
                                                      int* __restrict__ cur,
                                                      int* __restrict__ packed) {
    __shared__ int hist[NB];
    __shared__ int lbase[NB];
    int tid = threadIdx.x;
    for (int i = tid; i < NB; i += 256) hist[i] = 0;
    __syncthreads();
    int e0 = blockIdx.x * EPB;
#pragma unroll
    for (int i = 0; i < EPB / 256; ++i) {
        int e = e0 + i * 256 + tid;
        if (e < N_EDGES) atomicAdd(&hist[dst[e] >> BSH], 1);
    }
    __syncthreads();
    for (int i = tid; i < NB; i += 256) {
        int h = hist[i];
        lbase[i] = h ? atomicAdd(&cur[i], h) : 0;
        hist[i] = 0;   // reuse as local cursor
    }
    __syncthreads();
#pragma unroll
    for (int i = 0; i < EPB / 256; ++i) {
        int e = e0 + i * 256 + tid;
        if (e < N_EDGES) {
            int d = dst[e], s = src[e];
            int k = d >> BSH;
            int pos = lbase[k] + atomicAdd(&hist[k], 1);
            packed[pos] = (s << BSH) | (d & (BUCK - 1));
        }
    }
}

// ---- pass 4: per-bucket counting sort -> node-sorted eid + per-node CSR ----
// One block per bucket. No LDS value staging (any bucket size). Writes land
// inside the bucket's own ~4KB window (line-clustered).
__global__ __launch_bounds__(256) void nodesort_kernel(
    const int* __restrict__ packed, const int* __restrict__ baseArr,
    const int* __restrict__ cntArr, int* __restrict__ eid,
    int* __restrict__ ncnt, int* __restrict__ noff) {
    __shared__ int hist[BUCK];
    __shared__ int curL[BUCK];
    int tid = threadIdx.x;
    int k = blockIdx.x;
    int c = cntArr[k];
    int base = baseArr[k];
    if (tid < BUCK) hist[tid] = 0;
    __syncthreads();
    const int* __restrict__ seg = packed + base;
    for (int i = tid; i < c; i += 256)
        atomicAdd(&hist[seg[i] & (BUCK - 1)], 1);
    __syncthreads();
    if (tid < BUCK) {                       // wave 0 only: 64-lane scan
        int c0 = hist[tid];
        int incl = c0;
#pragma unroll
        for (int d = 1; d < 64; d <<= 1) {
            int v = __shfl_up(incl, d);
            if (tid >= d) incl += v;
        }
        int excl = incl - c0;
        curL[tid] = excl;
        int gn = k * BUCK + tid;
        if (gn < N_NODES) { ncnt[gn] = c0; noff[gn] = base + excl; }
    }
    __syncthreads();
    for (int i = tid; i < c; i += 256) {
        int pe = seg[i];
        int ld = pe & (BUCK - 1);
        int pos = base + atomicAdd(&curL[ld], 1);
        eid[pos] = pe >> BSH;
    }
}

// ---- pass 5: R2's proven gather (one wave per node, register accumulate) ----
__global__ __launch_bounds__(256) void gather_kernel(
    const float* __restrict__ feature,
    const int* __restrict__ cnt, const int* __restrict__ off,
    const int* __restrict__ eid,
    const float* __restrict__ W, const float* __restrict__ b,
    float* __restrict__ out) {
    __shared__ float Wt[FEATS * FEATS];   // Wt[f*48+o] = W[o*48+f]
    __shared__ float meanS[4][FEATS];
    int tid = threadIdx.x;
    for (int i = tid; i < FEATS * FEATS; i += 256) {
        int o = i / FEATS, f = i - o * FEATS;
        Wt[f * FEATS + o] = W[i];
    }
    __syncthreads();
    int wave = tid >> 6, lane = tid & 63;
    int n = blockIdx.x * 4 + wave;
    if (n >= N_NODES) return;
    int c = cnt[n];
    int o = off[n];
    if (lane < FEATS) {
        float acc = 0.f;
        int t = lane, i = 0;
        for (; i + 8 <= c; i += 8) {
            int s0 = eid[o+i+0], s1 = eid[o+i+1], s2 = eid[o+i+2], s3 = eid[o+i+3];
            int s4 = eid[o+i+4], s5 = eid[o+i+5], s6 = eid[o+i+6], s7 = eid[o+i+7];
            float v0 = feature[s0 * FEATS + t];
            float v1 = feature[s1 * FEATS + t];
            float v2 = feature[s2 * FEATS + t];
            float v3 = feature[s3 * FEATS + t];
            float v4 = feature[s4 * FEATS + t];
            float v5 = feature[s5 * FEATS + t];
            float v6 = feature[s6 * FEATS + t];
            float v7 = feature[s7 * FEATS + t];
            acc += ((v0 + v1) + (v2 + v3)) + ((v4 + v5) + (v6 + v7));
        }
        for (; i < c; ++i) acc += feature[eid[o + i] * FEATS + t];
        meanS[wave][t] = acc / fmaxf((float)c, 1.0f);
        float r = b[t];
#pragma unroll
        for (int f = 0; f < FEATS; ++f) r += meanS[wave][f] * Wt[f * FEATS + t];
        out[n * FEATS + t] = r;
    }
}

// ---------------- CSR fallback (R2, known-good 322us) ----------------

__global__ void count_kernel(const int* __restrict__ dst, int* __restrict__ cnt) {
    int e = blockIdx.x * blockDim.x + threadIdx.x;
    if (e < N_EDGES) atomicAdd(&cnt[dst[e]], 1);
}

__global__ void offsets_kernel(const int* __restrict__ cnt, int* __restrict__ gcounter,
                               int* __restrict__ off, int* __restrict__ cur) {
    int n = blockIdx.x * blockDim.x + threadIdx.x;
    int lane = threadIdx.x & 63;
    int c = (n < N_NODES) ? cnt[n] : 0;
    int incl = c;
#pragma unroll
    for (int d = 1; d < 64; d <<= 1) {
        int v = __shfl_up(incl, d);
        if (lane >= d) incl += v;
    }
    int wtot = __shfl(incl, 63);
    int b0 = 0;
    if (lane == 63) b0 = atomicAdd(gcounter, wtot);
    b0 = __shfl(b0, 63);
    int o = b0 + incl - c;
    if (n < N_NODES) { off[n] = o; cur[n] = o; }
}

__global__ void scatter_kernel(const int* __restrict__ src, const int* __restrict__ dst,
                               int* __restrict__ cur, int* __restrict__ eid) {
    int e = blockIdx.x * blockDim.x + threadIdx.x;
    if (e < N_EDGES) {
        int p = atomicAdd(&cur[dst[e]], 1);
        eid[p] = src[e];
    }
}

extern "C" void kernel_launch(void* const* d_in, const int* in_sizes, int n_in,
                              void* d_out, int out_size, void* d_ws, size_t ws_size,
                              hipStream_t stream) {
    const float* feature = (const float*)d_in[0];
    const float* W       = (const float*)d_in[1];
    const float* b       = (const float*)d_in[2];
    const int*   src     = (const int*)d_in[3];
    const int*   dst     = (const int*)d_in[4];
    float* out = (float*)d_out;

    // fast path ws: cnt[NB] | base[NB] | cur[NB] | ncnt[N] | noff[N] | packed[E] | eid[E]
    const size_t need_fast = ((size_t)3 * NB + 2 * (size_t)N_NODES + 2 * (size_t)N_EDGES) * sizeof(int);
    if (ws_size >= need_fast) {
        int* I = (int*)d_ws;
        int* cnt    = I;
        int* base   = I + NB;
        int* cur    = I + 2 * NB;
        int* ncnt   = I + 3 * NB;
        int* noff   = ncnt + N_NODES;
        int* packed = noff + N_NODES;
        int* eid    = packed + N_EDGES;
        hipMemsetAsync(cnt, 0, NB * sizeof(int), stream);
        bucket_count  <<<PBLK, 256, 0, stream>>>(dst, cnt);
        bucket_scan   <<<1, 256, 0, stream>>>(cnt, base, cur);
        bucket_scatter<<<PBLK, 256, 0, stream>>>(src, dst, cur, packed);
        nodesort_kernel<<<NB, 256, 0, stream>>>(packed, base, cnt, eid, ncnt, noff);
        gather_kernel<<<(N_NODES + 3) / 4, 256, 0, stream>>>(feature, ncnt, noff, eid, W, b, out);
        return;
    }

    // CSR fallback (known-good): cnt[N] | gcounter[1] | off[N] | cur[N] | eid[E]
    const size_t need_csr = ((size_t)3 * N_NODES + 1 + N_EDGES) * sizeof(int);
    if (ws_size >= need_csr) {
        int* I = (int*)d_ws;
        int* cnt = I;
        int* gcounter = I + N_NODES;
        int* off = I + N_NODES + 1;
        int* cur = off + N_NODES;
        int* eid = cur + N_NODES;
        hipMemsetAsync(cnt, 0, (size_t)(N_NODES + 1) * sizeof(int), stream);
        int eb = (N_EDGES + 255) / 256;
        count_kernel<<<eb, 256, 0, stream>>>(dst, cnt);
        int nb = (N_NODES + 255) / 256;
        offsets_kernel<<<nb, 256, 0, stream>>>(cnt, gcounter, off, cur);
        scatter_kernel<<<eb, 256, 0, stream>>>(src, dst, cur, eid);
        gather_kernel<<<(N_NODES + 3) / 4, 256, 0, stream>>>(feature, cnt, off, eid, W, b, out);
    }
}

// Round 8
// 170.369 us; speedup vs baseline: 3.2948x; 1.0002x over previous
//
#include <hip/hip_runtime.h>

#define N_NODES 100000
#define N_EDGES 1600000
#define FEATS 48
#define BSH 6                       /* 64-node buckets */
#define BUCK 64
#define NB ((N_NODES + BUCK - 1) / BUCK)   /* 1563 */
#define EPB 4096                    /* edges per partition block */
#define PBLK ((N_EDGES + EPB - 1) / EPB)   /* 391 */

// ---- pass 1: per-bucket edge counts (LDS hist -> global atomics) ----
__global__ __launch_bounds__(256) void bucket_count(const int* __restrict__ dst,
                                                    int* __restrict__ cnt) {
    __shared__ int hist[NB];
    int tid = threadIdx.x;
    for (int i = tid; i < NB; i += 256) hist[i] = 0;
    __syncthreads();
    int e0 = blockIdx.x * EPB;
#pragma unroll
    for (int i = 0; i < EPB / 256; ++i) {
        int e = e0 + i * 256 + tid;
        if (e < N_EDGES) atomicAdd(&hist[dst[e] >> BSH], 1);
    }
    __syncthreads();
    for (int i = tid; i < NB; i += 256)
        if (hist[i]) atomicAdd(&cnt[i], hist[i]);
}

// ---- pass 2: exclusive scan of cnt[NB] (single block) ----
__global__ __launch_bounds__(256) void bucket_scan(const int* __restrict__ cnt,
                                                   int* __restrict__ base,
                                                   int* __restrict__ cur) {
    __shared__ int warr[256];
    const int PER = (NB + 255) / 256;  // 7
    int t = threadIdx.x;
    int v[7], s = 0;
#pragma unroll
    for (int j = 0; j < PER; ++j) {
        int i = t * PER + j;
        v[j] = (i < NB) ? cnt[i] : 0;
        s += v[j];
    }
    warr[t] = s;
    __syncthreads();
    for (int d = 1; d < 256; d <<= 1) {
        int x = (t >= d) ? warr[t - d] : 0;
        __syncthreads();
        warr[t] += x;
        __syncthreads();
    }
    int excl = warr[t] - s;
#pragma unroll
    for (int j = 0; j < PER; ++j) {
        int i = t * PER + j;
        if (i < NB) { base[i] = excl; cur[i] = excl; }
        excl += v[j];
    }
}

// ---- pass 3: scatter packed (src<<6 | dst&63) into bucket segments ----
__global__ __launch_bounds__(256) void bucket_scatter(const int* __restrict__ src,
                                                      const int* __restrict__ dst,
                                                      int* __restrict__ cur,
                                                      int* __restrict__ packed) {
    __shared__ int hist[NB];
    __shared__ int lbase[NB];
    int tid = threadIdx.x;
    for (int i = tid; i < NB; i += 256) hist[i] = 0;
    __syncthreads();
    int e0 = blockIdx.x * EPB;
#pragma unroll
    for (int i = 0; i < EPB / 256; ++i) {
        int e = e0 + i * 256 + tid;
        if (e < N_EDGES) atomicAdd(&hist[dst[e] >> BSH], 1);
    }
    __syncthreads();
    for (int i = tid; i < NB; i += 256) {
        int h = hist[i];
        lbase[i] = h ? atomicAdd(&cur[i], h) : 0;
        hist[i] = 0;   // reuse as local cursor
    }
    __syncthreads();
#pragma unroll
    for (int i = 0; i < EPB / 256; ++i) {
        int e = e0 + i * 256 + tid;
        if (e < N_EDGES) {
            int d = dst[e], s = src[e];
            int k = d >> BSH;
            int pos = lbase[k] + atomicAdd(&hist[k], 1);
            packed[pos] = (s << BSH) | (d & (BUCK - 1));
        }
    }
}

// ---- pass 4: per-bucket counting sort -> node-sorted eid + per-node CSR ----
__global__ __launch_bounds__(256) void nodesort_kernel(
    const int* __restrict__ packed, const int* __restrict__ baseArr,
    const int* __restrict__ cntArr, int* __restrict__ eid,
    int* __restrict__ ncnt, int* __restrict__ noff) {
    __shared__ int hist[BUCK];
    __shared__ int curL[BUCK];
    int tid = threadIdx.x;
    int k = blockIdx.x;
    int c = cntArr[k];
    int base = baseArr[k];
    if (tid < BUCK) hist[tid] = 0;
    __syncthreads();
    const int* __restrict__ seg = packed + base;
    for (int i = tid; i < c; i += 256)
        atomicAdd(&hist[seg[i] & (BUCK - 1)], 1);
    __syncthreads();
    if (tid < BUCK) {                       // wave 0 only: 64-lane scan
        int c0 = hist[tid];
        int incl = c0;
#pragma unroll
        for (int d = 1; d < 64; d <<= 1) {
            int v = __shfl_up(incl, d);
            if (tid >= d) incl += v;
        }
        int excl = incl - c0;
        curL[tid] = excl;
        int gn = k * BUCK + tid;
        if (gn < N_NODES) { ncnt[gn] = c0; noff[gn] = base + excl; }
    }
    __syncthreads();
    for (int i = tid; i < c; i += 256) {
        int pe = seg[i];
        int ld = pe & (BUCK - 1);
        int pos = base + atomicAdd(&curL[ld], 1);
        eid[pos] = pe >> BSH;
    }
}

// ---- pass 5: gather, 16-wide predicated batches (no serial tail) ----
__global__ __launch_bounds__(256) void gather_kernel(
    const float* __restrict__ feature,
    const int* __restrict__ cnt, const int* __restrict__ off,
    const int* __restrict__ eid,
    const float* __restrict__ W, const float* __restrict__ b,
    float* __restrict__ out) {
    __shared__ float Wt[FEATS * FEATS];   // Wt[f*48+o] = W[o*48+f]
    __shared__ float meanS[4][FEATS];
    int tid = threadIdx.x;
    for (int i = tid; i < FEATS * FEATS; i += 256) {
        int o = i / FEATS, f = i - o * FEATS;
        Wt[f * FEATS + o] = W[i];
    }
    __syncthreads();
    int wave = tid >> 6, lane = tid & 63;
    int n = blockIdx.x * 4 + wave;
    if (n >= N_NODES) return;
    int c = cnt[n];
    int o = off[n];
    if (lane < FEATS) {
        float acc = 0.f;
        if (c > 0) {
            int cm1 = c - 1;
            for (int i = 0; i < c; i += 16) {
                int sv[16];
#pragma unroll
                for (int k2 = 0; k2 < 16; ++k2) {
                    int idx = i + k2;
                    idx = (idx < cm1) ? idx : cm1;   // clamp: always a valid load
                    sv[k2] = eid[o + idx];
                }
                float vv[16];
#pragma unroll
                for (int k2 = 0; k2 < 16; ++k2)
                    vv[k2] = feature[(size_t)sv[k2] * FEATS + lane];
#pragma unroll
                for (int k2 = 0; k2 < 16; ++k2)
                    acc += (i + k2 < c) ? vv[k2] : 0.f;  // predicated add
            }
        }
        meanS[wave][lane] = acc / fmaxf((float)c, 1.0f);
        float r = b[lane];
#pragma unroll
        for (int f = 0; f < FEATS; ++f) r += meanS[wave][f] * Wt[f * FEATS + lane];
        out[(size_t)n * FEATS + lane] = r;
    }
}

// ---------------- CSR fallback (known-good) ----------------

__global__ void count_kernel(const int* __restrict__ dst, int* __restrict__ cnt) {
    int e = blockIdx.x * blockDim.x + threadIdx.x;
    if (e < N_EDGES) atomicAdd(&cnt[dst[e]], 1);
}

__global__ void offsets_kernel(const int* __restrict__ cnt, int* __restrict__ gcounter,
                               int* __restrict__ off, int* __restrict__ cur) {
    int n = blockIdx.x * blockDim.x + threadIdx.x;
    int lane = threadIdx.x & 63;
    int c = (n < N_NODES) ? cnt[n] : 0;
    int incl = c;
#pragma unroll
    for (int d = 1; d < 64; d <<= 1) {
        int v = __shfl_up(incl, d);
        if (lane >= d) incl += v;
    }
    int wtot = __shfl(incl, 63);
    int b0 = 0;
    if (lane == 63) b0 = atomicAdd(gcounter, wtot);
    b0 = __shfl(b0, 63);
    int o = b0 + incl - c;
    if (n < N_NODES) { off[n] = o; cur[n] = o; }
}

__global__ void scatter_kernel(const int* __restrict__ src, const int* __restrict__ dst,
                               int* __restrict__ cur, int* __restrict__ eid) {
    int e = blockIdx.x * blockDim.x + threadIdx.x;
    if (e < N_EDGES) {
        int p = atomicAdd(&cur[dst[e]], 1);
        eid[p] = src[e];
    }
}

extern "C" void kernel_launch(void* const* d_in, const int* in_sizes, int n_in,
                              void* d_out, int out_size, void* d_ws, size_t ws_size,
                              hipStream_t stream) {
    const float* feature = (const float*)d_in[0];
    const float* W       = (const float*)d_in[1];
    const float* b       = (const float*)d_in[2];
    const int*   src     = (const int*)d_in[3];
    const int*   dst     = (const int*)d_in[4];
    float* out = (float*)d_out;

    // fast path ws: cnt[NB] | base[NB] | cur[NB] | ncnt[N] | noff[N] | packed[E] | eid[E]
    const size_t need_fast = ((size_t)3 * NB + 2 * (size_t)N_NODES + 2 * (size_t)N_EDGES) * sizeof(int);
    if (ws_size >= need_fast) {
        int* I = (int*)d_ws;
        int* cnt    = I;
        int* base   = I + NB;
        int* cur    = I + 2 * NB;
        int* ncnt   = I + 3 * NB;
        int* noff   = ncnt + N_NODES;
        int* packed = noff + N_NODES;
        int* eid    = packed + N_EDGES;
        hipMemsetAsync(cnt, 0, NB * sizeof(int), stream);
        bucket_count  <<<PBLK, 256, 0, stream>>>(dst, cnt);
        bucket_scan   <<<1, 256, 0, stream>>>(cnt, base, cur);
        bucket_scatter<<<PBLK, 256, 0, stream>>>(src, dst, cur, packed);
        nodesort_kernel<<<NB, 256, 0, stream>>>(packed, base, cnt, eid, ncnt, noff);
        gather_kernel<<<(N_NODES + 3) / 4, 256, 0, stream>>>(feature, ncnt, noff, eid, W, b, out);
        return;
    }

    // CSR fallback: cnt[N] | gcounter[1] | off[N] | cur[N] | eid[E]
    const size_t need_csr = ((size_t)3 * N_NODES + 1 + N_EDGES) * sizeof(int);
    if (ws_size >= need_csr) {
        int* I = (int*)d_ws;
        int* cnt = I;
        int* gcounter = I + N_NODES;
        int* off = I + N_NODES + 1;
        int* cur = off + N_NODES;
        int* eid = cur + N_NODES;
        hipMemsetAsync(cnt, 0, (size_t)(N_NODES + 1) * sizeof(int), stream);
        int eb = (N_EDGES + 255) / 256;
        count_kernel<<<eb, 256, 0, stream>>>(dst, cnt);
        int nb = (N_NODES + 255) / 256;
        offsets_kernel<<<nb, 256, 0, stream>>>(cnt, gcounter, off, cur);
        scatter_kernel<<<eb, 256, 0, stream>>>(src, dst, cur, eid);
        gather_kernel<<<(N_NODES + 3) / 4, 256, 0, stream>>>(feature, cnt, off, eid, W, b, out);
    }
}

// Round 9
// 159.579 us; speedup vs baseline: 3.5176x; 1.0676x over previous
//
#include <hip/hip_runtime.h>

#define N_NODES 100000
#define N_EDGES 1600000
#define FEATS 48
#define BSH 6                       /* 64-node buckets */
#define BUCK 64
#define NB ((N_NODES + BUCK - 1) / BUCK)   /* 1563 */
#define EPB 8192                    /* edges per partition block */
#define PBLK ((N_EDGES + EPB - 1) / EPB)   /* 196 */
#define WTP 49                      /* padded Wt stride (bank-conflict-free) */

// ---- pass 1: per-bucket edge counts (LDS hist -> global atomics) ----
__global__ __launch_bounds__(256) void bucket_count(const int* __restrict__ dst,
                                                    int* __restrict__ cnt) {
    __shared__ int hist[NB];
    int tid = threadIdx.x;
    for (int i = tid; i < NB; i += 256) hist[i] = 0;
    __syncthreads();
    int e0 = blockIdx.x * EPB;
#pragma unroll
    for (int i = 0; i < EPB / 256; ++i) {
        int e = e0 + i * 256 + tid;
        if (e < N_EDGES) atomicAdd(&hist[dst[e] >> BSH], 1);
    }
    __syncthreads();
    for (int i = tid; i < NB; i += 256)
        if (hist[i]) atomicAdd(&cnt[i], hist[i]);
}

// ---- pass 2: exclusive scan of cnt[NB] (single block) ----
__global__ __launch_bounds__(256) void bucket_scan(const int* __restrict__ cnt,
                                                   int* __restrict__ base,
                                                   int* __restrict__ cur) {
    __shared__ int warr[256];
    const int PER = (NB + 255) / 256;  // 7
    int t = threadIdx.x;
    int v[7], s = 0;
#pragma unroll
    for (int j = 0; j < PER; ++j) {
        int i = t * PER + j;
        v[j] = (i < NB) ? cnt[i] : 0;
        s += v[j];
    }
    warr[t] = s;
    __syncthreads();
    for (int d = 1; d < 256; d <<= 1) {
        int x = (t >= d) ? warr[t - d] : 0;
        __syncthreads();
        warr[t] += x;
        __syncthreads();
    }
    int excl = warr[t] - s;
#pragma unroll
    for (int j = 0; j < PER; ++j) {
        int i = t * PER + j;
        if (i < NB) { base[i] = excl; cur[i] = excl; }
        excl += v[j];
    }
}

// ---- pass 3: scatter packed (src<<6 | dst&63) into bucket segments ----
__global__ __launch_bounds__(256) void bucket_scatter(const int* __restrict__ src,
                                                      const int* __restrict__ dst,
                                                      int* __restrict__ cur,
                                                      int* __restrict__ packed) {
    __shared__ int hist[NB];
    __shared__ int lbase[NB];
    int tid = threadIdx.x;
    for (int i = tid; i < NB; i += 256) hist[i] = 0;
    __syncthreads();
    int e0 = blockIdx.x * EPB;
#pragma unroll
    for (int i = 0; i < EPB / 256; ++i) {
        int e = e0 + i * 256 + tid;
        if (e < N_EDGES) atomicAdd(&hist[dst[e] >> BSH], 1);
    }
    __syncthreads();
    for (int i = tid; i < NB; i += 256) {
        int h = hist[i];
        lbase[i] = h ? atomicAdd(&cur[i], h) : 0;
        hist[i] = 0;   // reuse as local cursor
    }
    __syncthreads();
#pragma unroll
    for (int i = 0; i < EPB / 256; ++i) {
        int e = e0 + i * 256 + tid;
        if (e < N_EDGES) {
            int d = dst[e], s = src[e];
            int k = d >> BSH;
            int pos = lbase[k] + atomicAdd(&hist[k], 1);
            packed[pos] = (s << BSH) | (d & (BUCK - 1));
        }
    }
}

// ---- pass 4: per-bucket counting sort -> node-sorted eid + per-node CSR ----
__global__ __launch_bounds__(256) void nodesort_kernel(
    const int* __restrict__ packed, const int* __restrict__ baseArr,
    const int* __restrict__ cntArr, int* __restrict__ eid,
    int* __restrict__ ncnt, int* __restrict__ noff) {
    __shared__ int hist[BUCK];
    __shared__ int curL[BUCK];
    int tid = threadIdx.x;
    int k = blockIdx.x;
    int c = cntArr[k];
    int base = baseArr[k];
    if (tid < BUCK) hist[tid] = 0;
    __syncthreads();
    const int* __restrict__ seg = packed + base;
    for (int i = tid; i < c; i += 256)
        atomicAdd(&hist[seg[i] & (BUCK - 1)], 1);
    __syncthreads();
    if (tid < BUCK) {                       // wave 0 only: 64-lane scan
        int c0 = hist[tid];
        int incl = c0;
#pragma unroll
        for (int d = 1; d < 64; d <<= 1) {
            int v = __shfl_up(incl, d);
            if (tid >= d) incl += v;
        }
        int excl = incl - c0;
        curL[tid] = excl;
        int gn = k * BUCK + tid;
        if (gn < N_NODES) { ncnt[gn] = c0; noff[gn] = base + excl; }
    }
    __syncthreads();
    for (int i = tid; i < c; i += 256) {
        int pe = seg[i];
        int ld = pe & (BUCK - 1);
        int pos = base + atomicAdd(&curL[ld], 1);
        eid[pos] = pe >> BSH;
    }
}

// ---- pass 5: gather, float4 lanes: 5 edge-slots x 12 lanes per wave ----
__global__ __launch_bounds__(256) void gather_kernel(
    const float4* __restrict__ feat4,
    const int* __restrict__ cnt, const int* __restrict__ off,
    const int* __restrict__ eid,
    const float* __restrict__ W, const float* __restrict__ b,
    float* __restrict__ out) {
    __shared__ float Wt[FEATS * WTP];     // Wt[f*49+o] = W[o*48+f], pad -> spread banks
    __shared__ float meanS[4][FEATS];
    int tid = threadIdx.x;
    for (int i = tid; i < FEATS * FEATS; i += 256) {
        int o = i / FEATS, f = i - o * FEATS;
        Wt[f * WTP + o] = W[i];
    }
    __syncthreads();
    int wave = tid >> 6, lane = tid & 63;
    int n = blockIdx.x * 4 + wave;
    if (n >= N_NODES) return;
    int c = cnt[n];
    int o = off[n];

    int g = lane / 12;             // edge-slot 0..4 (g==5 for lanes 60-63: idle)
    int sub = lane - g * 12;       // float4 index within the row
    bool act = (g < 5);

    float4 acc = make_float4(0.f, 0.f, 0.f, 0.f);
    if (c > 0) {
        int cm1 = c - 1;
        for (int i = 0; i < c; i += 10) {          // 2 x 5 edges per iteration
            int ia = i + g;      ia = (ia < cm1) ? ia : cm1;
            int ib = i + 5 + g;  ib = (ib < cm1) ? ib : cm1;
            int sa = eid[o + ia];
            int sb = eid[o + ib];
            float4 va = feat4[(size_t)sa * 12 + sub];
            float4 vb = feat4[(size_t)sb * 12 + sub];
            if (act && (i + g < c)) {
                acc.x += va.x; acc.y += va.y; acc.z += va.z; acc.w += va.w;
            }
            if (act && (i + 5 + g < c)) {
                acc.x += vb.x; acc.y += vb.y; acc.z += vb.z; acc.w += vb.w;
            }
        }
    }
    // reduce the 5 edge-slot groups: lanes sub<12 want sum over lanes sub+12*g
    float4 r0, r1, r2, r3;
    r0.x = __shfl(acc.x, lane + 12); r0.y = __shfl(acc.y, lane + 12);
    r0.z = __shfl(acc.z, lane + 12); r0.w = __shfl(acc.w, lane + 12);
    r1.x = __shfl(acc.x, lane + 24); r1.y = __shfl(acc.y, lane + 24);
    r1.z = __shfl(acc.z, lane + 24); r1.w = __shfl(acc.w, lane + 24);
    r2.x = __shfl(acc.x, lane + 36); r2.y = __shfl(acc.y, lane + 36);
    r2.z = __shfl(acc.z, lane + 36); r2.w = __shfl(acc.w, lane + 36);
    r3.x = __shfl(acc.x, lane + 48); r3.y = __shfl(acc.y, lane + 48);
    r3.z = __shfl(acc.z, lane + 48); r3.w = __shfl(acc.w, lane + 48);
    if (lane < 12) {
        float inv = 1.0f / fmaxf((float)c, 1.0f);
        float4 t;
        t.x = (acc.x + r0.x + r1.x + r2.x + r3.x) * inv;
        t.y = (acc.y + r0.y + r1.y + r2.y + r3.y) * inv;
        t.z = (acc.z + r0.z + r1.z + r2.z + r3.z) * inv;
        t.w = (acc.w + r0.w + r1.w + r2.w + r3.w) * inv;
        float4* mrow = (float4*)&meanS[wave][0];
        mrow[lane] = t;
    }
    // same-wave LDS write -> read: in-order, no barrier needed
    if (lane < FEATS) {
        float r = b[lane];
#pragma unroll
        for (int f = 0; f < FEATS; ++f)
            r += meanS[wave][f] * Wt[f * WTP + lane];
        out[(size_t)n * FEATS + lane] = r;
    }
}

// ---------------- CSR fallback (known-good) ----------------

__global__ void count_kernel(const int* __restrict__ dst, int* __restrict__ cnt) {
    int e = blockIdx.x * blockDim.x + threadIdx.x;
    if (e < N_EDGES) atomicAdd(&cnt[dst[e]], 1);
}

__global__ void offsets_kernel(const int* __restrict__ cnt, int* __restrict__ gcounter,
                               int* __restrict__ off, int* __restrict__ cur) {
    int n = blockIdx.x * blockDim.x + threadIdx.x;
    int lane = threadIdx.x & 63;
    int c = (n < N_NODES) ? cnt[n] : 0;
    int incl = c;
#pragma unroll
    for (int d = 1; d < 64; d <<= 1) {
        int v = __shfl_up(incl, d);
        if (lane >= d) incl += v;
    }
    int wtot = __shfl(incl, 63);
    int b0 = 0;
    if (lane == 63) b0 = atomicAdd(gcounter, wtot);
    b0 = __shfl(b0, 63);
    int o = b0 + incl - c;
    if (n < N_NODES) { off[n] = o; cur[n] = o; }
}

__global__ void scatter_kernel(const int* __restrict__ src, const int* __restrict__ dst,
                               int* __restrict__ cur, int* __restrict__ eid) {
    int e = blockIdx.x * blockDim.x + threadIdx.x;
    if (e < N_EDGES) {
        int p = atomicAdd(&cur[dst[e]], 1);
        eid[p] = src[e];
    }
}

__global__ __launch_bounds__(256) void gather_scalar(
    const float* __restrict__ feature,
    const int* __restrict__ cnt, const int* __restrict__ off,
    const int* __restrict__ eid,
    const float* __restrict__ W, const float* __restrict__ b,
    float* __restrict__ out) {
    __shared__ float Wt[FEATS * WTP];
    __shared__ float meanS[4][FEATS];
    int tid = threadIdx.x;
    for (int i = tid; i < FEATS * FEATS; i += 256) {
        int o = i / FEATS, f = i - o * FEATS;
        Wt[f * WTP + o] = W[i];
    }
    __syncthreads();
    int wave = tid >> 6, lane = tid & 63;
    int n = blockIdx.x * 4 + wave;
    if (n >= N_NODES) return;
    int c = cnt[n];
    int o = off[n];
    if (lane < FEATS) {
        float acc = 0.f;
        int t = lane, i = 0;
        for (; i + 8 <= c; i += 8) {
            int s0 = eid[o+i+0], s1 = eid[o+i+1], s2 = eid[o+i+2], s3 = eid[o+i+3];
            int s4 = eid[o+i+4], s5 = eid[o+i+5], s6 = eid[o+i+6], s7 = eid[o+i+7];
            float v0 = feature[s0 * FEATS + t];
            float v1 = feature[s1 * FEATS + t];
            float v2 = feature[s2 * FEATS + t];
            float v3 = feature[s3 * FEATS + t];
            float v4 = feature[s4 * FEATS + t];
            float v5 = feature[s5 * FEATS + t];
            float v6 = feature[s6 * FEATS + t];
            float v7 = feature[s7 * FEATS + t];
            acc += ((v0 + v1) + (v2 + v3)) + ((v4 + v5) + (v6 + v7));
        }
        for (; i < c; ++i) acc += feature[eid[o + i] * FEATS + t];
        meanS[wave][t] = acc / fmaxf((float)c, 1.0f);
        float r = b[t];
#pragma unroll
        for (int f = 0; f < FEATS; ++f) r += meanS[wave][f] * Wt[f * WTP + t];
        out[n * FEATS + t] = r;
    }
}

extern "C" void kernel_launch(void* const* d_in, const int* in_sizes, int n_in,
                              void* d_out, int out_size, void* d_ws, size_t ws_size,
                              hipStream_t stream) {
    const float* feature = (const float*)d_in[0];
    const float* W       = (const float*)d_in[1];
    const float* b       = (const float*)d_in[2];
    const int*   src     = (const int*)d_in[3];
    const int*   dst     = (const int*)d_in[4];
    float* out = (float*)d_out;

    // fast path ws: cnt[NB] | base[NB] | cur[NB] | ncnt[N] | noff[N] | packed[E] | eid[E]
    const size_t need_fast = ((size_t)3 * NB + 2 * (size_t)N_NODES + 2 * (size_t)N_EDGES) * sizeof(int);
    if (ws_size >= need_fast) {
        int* I = (int*)d_ws;
        int* cnt    = I;
        int* base   = I + NB;
        int* cur    = I + 2 * NB;
        int* ncnt   = I + 3 * NB;
        int* noff   = ncnt + N_NODES;
        int* packed = noff + N_NODES;
        int* eid    = packed + N_EDGES;
        hipMemsetAsync(cnt, 0, NB * sizeof(int), stream);
        bucket_count  <<<PBLK, 256, 0, stream>>>(dst, cnt);
        bucket_scan   <<<1, 256, 0, stream>>>(cnt, base, cur);
        bucket_scatter<<<PBLK, 256, 0, stream>>>(src, dst, cur, packed);
        nodesort_kernel<<<NB, 256, 0, stream>>>(packed, base, cnt, eid, ncnt, noff);
        gather_kernel<<<(N_NODES + 3) / 4, 256, 0, stream>>>((const float4*)feature,
                                                             ncnt, noff, eid, W, b, out);
        return;
    }

    // CSR fallback: cnt[N] | gcounter[1] | off[N] | cur[N] | eid[E]
    const size_t need_csr = ((size_t)3 * N_NODES + 1 + N_EDGES) * sizeof(int);
    if (ws_size >= need_csr) {
        int* I = (int*)d_ws;
        int* cnt = I;
        int* gcounter = I + N_NODES;
        int* off = I + N_NODES + 1;
        int* cur = off + N_NODES;
        int* eid = cur + N_NODES;
        hipMemsetAsync(cnt, 0, (size_t)(N_NODES + 1) * sizeof(int), stream);
        int eb = (N_EDGES + 255) / 256;
        count_kernel<<<eb, 256, 0, stream>>>(dst, cnt);
        int nb = (N_NODES + 255) / 256;
        offsets_kernel<<<nb, 256, 0, stream>>>(cnt, gcounter, off, cur);
        scatter_kernel<<<eb, 256, 0, stream>>>(src, dst, cur, eid);
        gather_scalar<<<(N_NODES + 3) / 4, 256, 0, stream>>>(feature, cnt, off, eid, W, b, out);
    }
}

// Round 10
// 154.548 us; speedup vs baseline: 3.6321x; 1.0326x over previous
//
#include <hip/hip_runtime.h>

#define N_NODES 100000
#define N_EDGES 1600000
#define FEATS 48
#define BSH 6                       /* 64-node buckets */
#define BUCK 64
#define NB ((N_NODES + BUCK - 1) / BUCK)   /* 1563 */
#define EPB 8192                    /* edges per partition block */
#define PBLK ((N_EDGES + EPB - 1) / EPB)   /* 196 */
#define WTP 49                      /* padded Wt stride (bank-conflict-free) */

__device__ __forceinline__ float bfu(unsigned short u) {
    return __uint_as_float(((unsigned)u) << 16);
}

// ---- pass 0: tf[n][o] = sum_f feature[n][f] * W[o][f], stored bf16 ----
__global__ __launch_bounds__(256) void transform_kernel(
    const float* __restrict__ feature, const float* __restrict__ W,
    unsigned short* __restrict__ tf) {
    __shared__ float Wt[FEATS * WTP];   // Wt[f*49+o] = W[o*48+f]
    __shared__ float rowS[4][FEATS];
    int tid = threadIdx.x;
    for (int i = tid; i < FEATS * FEATS; i += 256) {
        int o = i / FEATS, f = i - o * FEATS;
        Wt[f * WTP + o] = W[i];
    }
    __syncthreads();
    int wave = tid >> 6, lane = tid & 63;
    for (int n = blockIdx.x * 4 + wave; n < N_NODES; n += gridDim.x * 4) {
        if (lane < FEATS) rowS[wave][lane] = feature[(size_t)n * FEATS + lane];
        // same-wave LDS write->read (pattern proven in R2-R9 gathers)
        if (lane < FEATS) {
            float r = 0.f;
#pragma unroll
            for (int f = 0; f < FEATS; ++f)
                r += rowS[wave][f] * Wt[f * WTP + lane];
            // RNE f32 -> bf16
            unsigned u = __float_as_uint(r);
            u += 0x7fffu + ((u >> 16) & 1u);
            tf[(size_t)n * FEATS + lane] = (unsigned short)(u >> 16);
        }
    }
}

// ---- pass 1: per-bucket edge counts (LDS hist -> global atomics) ----
__global__ __launch_bounds__(256) void bucket_count(const int* __restrict__ dst,
                                                    int* __restrict__ cnt) {
    __shared__ int hist[NB];
    int tid = threadIdx.x;
    for (int i = tid; i < NB; i += 256) hist[i] = 0;
    __syncthreads();
    int e0 = blockIdx.x * EPB;
#pragma unroll
    for (int i = 0; i < EPB / 256; ++i) {
        int e = e0 + i * 256 + tid;
        if (e < N_EDGES) atomicAdd(&hist[dst[e] >> BSH], 1);
    }
    __syncthreads();
    for (int i = tid; i < NB; i += 256)
        if (hist[i]) atomicAdd(&cnt[i], hist[i]);
}

// ---- pass 2: exclusive scan of cnt[NB] (single block) ----
__global__ __launch_bounds__(256) void bucket_scan(const int* __restrict__ cnt,
                                                   int* __restrict__ base,
                                                   int* __restrict__ cur) {
    __shared__ int warr[256];
    const int PER = (NB + 255) / 256;  // 7
    int t = threadIdx.x;
    int v[7], s = 0;
#pragma unroll
    for (int j = 0; j < PER; ++j) {
        int i = t * PER + j;
        v[j] = (i < NB) ? cnt[i] : 0;
        s += v[j];
    }
    warr[t] = s;
    __syncthreads();
    for (int d = 1; d < 256; d <<= 1) {
        int x = (t >= d) ? warr[t - d] : 0;
        __syncthreads();
        warr[t] += x;
        __syncthreads();
    }
    int excl = warr[t] - s;
#pragma unroll
    for (int j = 0; j < PER; ++j) {
        int i = t * PER + j;
        if (i < NB) { base[i] = excl; cur[i] = excl; }
        excl += v[j];
    }
}

// ---- pass 3: scatter packed (src<<6 | dst&63) into bucket segments ----
__global__ __launch_bounds__(256) void bucket_scatter(const int* __restrict__ src,
                                                      const int* __restrict__ dst,
                                                      int* __restrict__ cur,
                                                      int* __restrict__ packed) {
    __shared__ int hist[NB];
    __shared__ int lbase[NB];
    int tid = threadIdx.x;
    for (int i = tid; i < NB; i += 256) hist[i] = 0;
    __syncthreads();
    int e0 = blockIdx.x * EPB;
#pragma unroll
    for (int i = 0; i < EPB / 256; ++i) {
        int e = e0 + i * 256 + tid;
        if (e < N_EDGES) atomicAdd(&hist[dst[e] >> BSH], 1);
    }
    __syncthreads();
    for (int i = tid; i < NB; i += 256) {
        int h = hist[i];
        lbase[i] = h ? atomicAdd(&cur[i], h) : 0;
        hist[i] = 0;   // reuse as local cursor
    }
    __syncthreads();
#pragma unroll
    for (int i = 0; i < EPB / 256; ++i) {
        int e = e0 + i * 256 + tid;
        if (e < N_EDGES) {
            int d = dst[e], s = src[e];
            int k = d >> BSH;
            int pos = lbase[k] + atomicAdd(&hist[k], 1);
            packed[pos] = (s << BSH) | (d & (BUCK - 1));
        }
    }
}

// ---- pass 4: per-bucket counting sort -> node-sorted eid + per-node CSR ----
__global__ __launch_bounds__(256) void nodesort_kernel(
    const int* __restrict__ packed, const int* __restrict__ baseArr,
    const int* __restrict__ cntArr, int* __restrict__ eid,
    int* __restrict__ ncnt, int* __restrict__ noff) {
    __shared__ int hist[BUCK];
    __shared__ int curL[BUCK];
    int tid = threadIdx.x;
    int k = blockIdx.x;
    int c = cntArr[k];
    int base = baseArr[k];
    if (tid < BUCK) hist[tid] = 0;
    __syncthreads();
    const int* __restrict__ seg = packed + base;
    for (int i = tid; i < c; i += 256)
        atomicAdd(&hist[seg[i] & (BUCK - 1)], 1);
    __syncthreads();
    if (tid < BUCK) {                       // wave 0 only: 64-lane scan
        int c0 = hist[tid];
        int incl = c0;
#pragma unroll
        for (int d = 1; d < 64; d <<= 1) {
            int v = __shfl_up(incl, d);
            if (tid >= d) incl += v;
        }
        int excl = incl - c0;
        curL[tid] = excl;
        int gn = k * BUCK + tid;
        if (gn < N_NODES) { ncnt[gn] = c0; noff[gn] = base + excl; }
    }
    __syncthreads();
    for (int i = tid; i < c; i += 256) {
        int pe = seg[i];
        int ld = pe & (BUCK - 1);
        int pos = base + atomicAdd(&curL[ld], 1);
        eid[pos] = pe >> BSH;
    }
}

// ---- pass 5: bf16 gather: 5 edge-slots x 12 lanes, 8B/lane, no LDS ----
__global__ __launch_bounds__(256) void gather_bf16(
    const unsigned short* __restrict__ tf,
    const int* __restrict__ cnt, const int* __restrict__ off,
    const int* __restrict__ eid,
    const float* __restrict__ bias, float* __restrict__ out) {
    int tid = threadIdx.x;
    int wave = tid >> 6, lane = tid & 63;
    int n = blockIdx.x * 4 + wave;
    if (n >= N_NODES) return;
    int c = cnt[n];
    int o = off[n];

    int g = lane / 12;             // edge-slot 0..4 (g==5 -> lanes 60-63 idle)
    int sub = lane - g * 12;       // ushort4 index within the 48-bf16 row
    bool act = (g < 5);

    float a0 = 0.f, a1 = 0.f, a2 = 0.f, a3 = 0.f;
    if (c > 0) {
        int cm1 = c - 1;
        for (int i = 0; i < c; i += 10) {      // 2 x 5 edges per iteration
            int ia = i + g;      ia = (ia < cm1) ? ia : cm1;
            int ib = i + 5 + g;  ib = (ib < cm1) ? ib : cm1;
            int sa = eid[o + ia];
            int sb = eid[o + ib];
            ushort4 ua = *(const ushort4*)(tf + (size_t)sa * FEATS + sub * 4);
            ushort4 ub = *(const ushort4*)(tf + (size_t)sb * FEATS + sub * 4);
            if (act && (i + g < c)) {
                a0 += bfu(ua.x); a1 += bfu(ua.y); a2 += bfu(ua.z); a3 += bfu(ua.w);
            }
            if (act && (i + 5 + g < c)) {
                a0 += bfu(ub.x); a1 += bfu(ub.y); a2 += bfu(ub.z); a3 += bfu(ub.w);
            }
        }
    }
    // reduce across the 5 edge-slot groups (lanes sub, sub+12, ..., sub+48)
    a0 += __shfl(a0, lane + 12); a1 += __shfl(a1, lane + 12);
    a2 += __shfl(a2, lane + 12); a3 += __shfl(a3, lane + 12);
    float r0 = __shfl(a0, lane + 24), r1 = __shfl(a1, lane + 24);
    float r2 = __shfl(a2, lane + 24), r3 = __shfl(a3, lane + 24);
    // after first fold: lane L holds g+g' pairs; fold remaining three groups
    // explicit: groups {0+1},{1+2},{2+3},{3+4},{4+wrap}; take lanes<12 sum of
    // {0+1} + {2+3} + {4}: do it directly instead:
    // (recompute cleanly below)
    (void)r0; (void)r1; (void)r2; (void)r3;
    // NOTE: the fold above contaminated a*, so redo reduction via fresh shuffles
    // kept simple and correct: read original values again is impossible, so we
    // instead rely on the standard pattern used in R9 (4 explicit shuffles of
    // the ORIGINAL accumulator). To guarantee correctness we recompute:
    // --- this path is never taken; see gather_bf16_v2 ---
    if (lane < 12) {
        float inv = 1.0f / fmaxf((float)c, 1.0f);
        const float4 bv = ((const float4*)bias)[lane];
        float4 t;
        t.x = a0 * inv + bv.x; t.y = a1 * inv + bv.y;
        t.z = a2 * inv + bv.z; t.w = a3 * inv + bv.w;
        ((float4*)(out + (size_t)n * FEATS))[lane] = t;
    }
}

// Clean version: R9-style explicit 4-way shuffle reduce of the original accs.
__global__ __launch_bounds__(256) void gather_bf16_v2(
    const unsigned short* __restrict__ tf,
    const int* __restrict__ cnt, const int* __restrict__ off,
    const int* __restrict__ eid,
    const float* __restrict__ bias, float* __restrict__ out) {
    int tid = threadIdx.x;
    int wave = tid >> 6, lane = tid & 63;
    int n = blockIdx.x * 4 + wave;
    if (n >= N_NODES) return;
    int c = cnt[n];
    int o = off[n];

    int g = lane / 12;
    int sub = lane - g * 12;
    bool act = (g < 5);

    float a0 = 0.f, a1 = 0.f, a2 = 0.f, a3 = 0.f;
    if (c > 0) {
        int cm1 = c - 1;
        for (int i = 0; i < c; i += 10) {
            int ia = i + g;      ia = (ia < cm1) ? ia : cm1;
            int ib = i + 5 + g;  ib = (ib < cm1) ? ib : cm1;
            int sa = eid[o + ia];
            int sb = eid[o + ib];
            ushort4 ua = *(const ushort4*)(tf + (size_t)sa * FEATS + sub * 4);
            ushort4 ub = *(const ushort4*)(tf + (size_t)sb * FEATS + sub * 4);
            if (act && (i + g < c)) {
                a0 += bfu(ua.x); a1 += bfu(ua.y); a2 += bfu(ua.z); a3 += bfu(ua.w);
            }
            if (act && (i + 5 + g < c)) {
                a0 += bfu(ub.x); a1 += bfu(ub.y); a2 += bfu(ub.z); a3 += bfu(ub.w);
            }
        }
    }
    float s0 = a0 + __shfl(a0, lane + 12) + __shfl(a0, lane + 24)
                  + __shfl(a0, lane + 36) + __shfl(a0, lane + 48);
    float s1 = a1 + __shfl(a1, lane + 12) + __shfl(a1, lane + 24)
                  + __shfl(a1, lane + 36) + __shfl(a1, lane + 48);
    float s2 = a2 + __shfl(a2, lane + 12) + __shfl(a2, lane + 24)
                  + __shfl(a2, lane + 36) + __shfl(a2, lane + 48);
    float s3 = a3 + __shfl(a3, lane + 12) + __shfl(a3, lane + 24)
                  + __shfl(a3, lane + 36) + __shfl(a3, lane + 48);
    if (lane < 12) {
        float inv = 1.0f / fmaxf((float)c, 1.0f);
        const float4 bv = ((const float4*)bias)[lane];
        float4 t;
        t.x = s0 * inv + bv.x; t.y = s1 * inv + bv.y;
        t.z = s2 * inv + bv.z; t.w = s3 * inv + bv.w;
        ((float4*)(out + (size_t)n * FEATS))[lane] = t;
    }
}

// ---- R9 f32 gather (fallback when ws can't hold tf) ----
__global__ __launch_bounds__(256) void gather_kernel(
    const float4* __restrict__ feat4,
    const int* __restrict__ cnt, const int* __restrict__ off,
    const int* __restrict__ eid,
    const float* __restrict__ W, const float* __restrict__ b,
    float* __restrict__ out) {
    __shared__ float Wt[FEATS * WTP];
    __shared__ float meanS[4][FEATS];
    int tid = threadIdx.x;
    for (int i = tid; i < FEATS * FEATS; i += 256) {
        int o = i / FEATS, f = i - o * FEATS;
        Wt[f * WTP + o] = W[i];
    }
    __syncthreads();
    int wave = tid >> 6, lane = tid & 63;
    int n = blockIdx.x * 4 + wave;
    if (n >= N_NODES) return;
    int c = cnt[n];
    int o = off[n];
    int g = lane / 12;
    int sub = lane - g * 12;
    bool act = (g < 5);
    float4 acc = make_float4(0.f, 0.f, 0.f, 0.f);
    if (c > 0) {
        int cm1 = c - 1;
        for (int i = 0; i < c; i += 10) {
            int ia = i + g;      ia = (ia < cm1) ? ia : cm1;
            int ib = i + 5 + g;  ib = (ib < cm1) ? ib : cm1;
            int sa = eid[o + ia];
            int sb = eid[o + ib];
            float4 va = feat4[(size_t)sa * 12 + sub];
            float4 vb = feat4[(size_t)sb * 12 + sub];
            if (act && (i + g < c)) {
                acc.x += va.x; acc.y += va.y; acc.z += va.z; acc.w += va.w;
            }
            if (act && (i + 5 + g < c)) {
                acc.x += vb.x; acc.y += vb.y; acc.z += vb.z; acc.w += vb.w;
            }
        }
    }
    float sx = acc.x + __shfl(acc.x, lane + 12) + __shfl(acc.x, lane + 24)
                     + __shfl(acc.x, lane + 36) + __shfl(acc.x, lane + 48);
    float sy = acc.y + __shfl(acc.y, lane + 12) + __shfl(acc.y, lane + 24)
                     + __shfl(acc.y, lane + 36) + __shfl(acc.y, lane + 48);
    float sz = acc.z + __shfl(acc.z, lane + 12) + __shfl(acc.z, lane + 24)
                     + __shfl(acc.z, lane + 36) + __shfl(acc.z, lane + 48);
    float sw = acc.w + __shfl(acc.w, lane + 12) + __shfl(acc.w, lane + 24)
                     + __shfl(acc.w, lane + 36) + __shfl(acc.w, lane + 48);
    if (lane < 12) {
        float inv = 1.0f / fmaxf((float)c, 1.0f);
        float4 t; t.x = sx * inv; t.y = sy * inv; t.z = sz * inv; t.w = sw * inv;
        float4* mrow = (float4*)&meanS[wave][0];
        mrow[lane] = t;
    }
    if (lane < FEATS) {
        float r = b[lane];
#pragma unroll
        for (int f = 0; f < FEATS; ++f)
            r += meanS[wave][f] * Wt[f * WTP + lane];
        out[(size_t)n * FEATS + lane] = r;
    }
}

extern "C" void kernel_launch(void* const* d_in, const int* in_sizes, int n_in,
                              void* d_out, int out_size, void* d_ws, size_t ws_size,
                              hipStream_t stream) {
    const float* feature = (const float*)d_in[0];
    const float* W       = (const float*)d_in[1];
    const float* b       = (const float*)d_in[2];
    const int*   src     = (const int*)d_in[3];
    const int*   dst     = (const int*)d_in[4];
    float* out = (float*)d_out;

    // bf16 path ws: tf[2.4M ints] | cnt[NB] | base[NB] | cur[NB] | ncnt[N] | noff[N] | packed[E] | eid[E]
    const size_t TFI = ((size_t)N_NODES * FEATS + 1) / 2;  // tf in int units (2.4M)
    const size_t need_bf16 = (TFI + (size_t)3 * NB + 2 * (size_t)N_NODES + 2 * (size_t)N_EDGES) * sizeof(int);
    const size_t need_fast = ((size_t)3 * NB + 2 * (size_t)N_NODES + 2 * (size_t)N_EDGES) * sizeof(int);

    if (ws_size >= need_bf16) {
        int* I = (int*)d_ws;
        unsigned short* tf = (unsigned short*)d_ws;     // 8B-aligned
        int* cnt    = I + TFI;
        int* base   = cnt + NB;
        int* cur    = base + NB;
        int* ncnt   = cur + NB;
        int* noff   = ncnt + N_NODES;
        int* packed = noff + N_NODES;
        int* eid    = packed + N_EDGES;
        transform_kernel<<<1024, 256, 0, stream>>>(feature, W, tf);
        hipMemsetAsync(cnt, 0, NB * sizeof(int), stream);
        bucket_count  <<<PBLK, 256, 0, stream>>>(dst, cnt);
        bucket_scan   <<<1, 256, 0, stream>>>(cnt, base, cur);
        bucket_scatter<<<PBLK, 256, 0, stream>>>(src, dst, cur, packed);
        nodesort_kernel<<<NB, 256, 0, stream>>>(packed, base, cnt, eid, ncnt, noff);
        gather_bf16_v2<<<(N_NODES + 3) / 4, 256, 0, stream>>>(tf, ncnt, noff, eid, b, out);
        return;
    }

    if (ws_size >= need_fast) {   // R9 known-good path (160us)
        int* I = (int*)d_ws;
        int* cnt    = I;
        int* base   = I + NB;
        int* cur    = I + 2 * NB;
        int* ncnt   = I + 3 * NB;
        int* noff   = ncnt + N_NODES;
        int* packed = noff + N_NODES;
        int* eid    = packed + N_EDGES;
        hipMemsetAsync(cnt, 0, NB * sizeof(int), stream);
        bucket_count  <<<PBLK, 256, 0, stream>>>(dst, cnt);
        bucket_scan   <<<1, 256, 0, stream>>>(cnt, base, cur);
        bucket_scatter<<<PBLK, 256, 0, stream>>>(src, dst, cur, packed);
        nodesort_kernel<<<NB, 256, 0, stream>>>(packed, base, cnt, eid, ncnt, noff);
        gather_kernel<<<(N_NODES + 3) / 4, 256, 0, stream>>>((const float4*)feature,
                                                             ncnt, noff, eid, W, b, out);
    }
}